// Round 12
// baseline (8483.454 us; speedup 1.0000x reference)
//
#include <hip/hip_runtime.h>
#include <hip/hip_fp16.h>
#include <cstdint>
#include <cstddef>

// ---------------------------------------------------------------------------
// CNN (conv1+pool, conv2+pool) -> seq [256][256][32]
// NTM scan: GROUPED PERSISTENT. 256 blocks x 1024 threads, 1 block/CU.
// 32 groups x 8 CUs. Each group handles 8 batches; each member CU owns
// 32 LSTM units (128 z-cols) with its fp16 weight slice (80 KB) resident in
// LDS -> ZERO per-step weight streaming (was 488 KB/step in R11).
// Per step: P1 z-slice GEMM (all 8 batches) -> LSTM(32 units x 8 b) ->
// [gsync1: h-slices via hEx] -> P3/P4/P5 for the HOME batch (R11's dense
// implementations) -> [gsync2: read-vectors via rEx] -> next step.
// Group members share an XCD (bb = m*32+g => bid%8 == g%8). Agent-scope
// atomics + release/acquire for cross-CU visibility. ctr zeroed per launch
// via hipMemsetAsync (captured in graph).
// ci pair slots: x 0..15, h 16..143; reads live in rEx (pairs 144..153,
// pads 154..159 zeroed once at init).
// ---------------------------------------------------------------------------

#define MW    20
#define NLOC  128
#define ZC    1024
#define PC    92
#define CLIPV 20.0f

__device__ __forceinline__ float sigmoidf_(float x) { return 1.0f / (1.0f + expf(-x)); }
__device__ __forceinline__ float softplusf_(float x) { return log1pf(expf(x)); }

__device__ __forceinline__ float dot2f(uint32_t w, uint32_t a, float c) {
    asm("v_dot2_f32_f16 %0, %1, %2, %0" : "+v"(c) : "v"(w), "v"(a));
    return c;
}

// ci-slot element e -> weight row: e<32 x (wx rows 0..31); e<288 h (wh);
// e<308 reads (wx rows 32..51); else pad 0.
__device__ __forceinline__ float wvalC(const float* wx, const float* wh, int e, int col) {
    if (e < 32)  return wx[e * ZC + col];
    if (e < 288) return wh[(e - 32) * ZC + col];
    if (e < 308) return wx[(e - 256) * ZC + col];
    return 0.0f;
}
__device__ __forceinline__ uint32_t packprC(const float* wx, const float* wh, int pr, int col) {
    __half2 h = __floats2half2_rn(wvalC(wx, wh, 2 * pr, col), wvalC(wx, wh, 2 * pr + 1, col));
    return *reinterpret_cast<uint32_t*>(&h);
}

// WslG: [m 0..7][pb 0..39][c 0..127][pq 0..3]; global col = (c>>5)*256+m*32+(c&31)
// hw2G: [128 up][92 col]
__global__ __launch_bounds__(256) void prep_pack(const float* __restrict__ wx,
                                                 const float* __restrict__ wh,
                                                 const float* __restrict__ hw,
                                                 uint32_t* __restrict__ WslG,
                                                 uint32_t* __restrict__ hw2G) {
    int idx = blockIdx.x * 256 + threadIdx.x;
    if (idx < 163840) {
        int pq = idx & 3;
        int c  = (idx >> 2) & 127;
        int rem = idx >> 9;            // m*40 + pb
        int pb = rem % 40, mm = rem / 40;
        int pair = pb * 4 + pq;
        int gcol = (c >> 5) * 256 + mm * 32 + (c & 31);
        WslG[idx] = packprC(wx, wh, pair, gcol);
    } else if (idx < 163840 + 11776) {
        int q = idx - 163840;
        int up = q / 92, col = q - up * 92;
        __half2 h = __floats2half2_rn(hw[(2 * up) * PC + col], hw[(2 * up + 1) * PC + col]);
        hw2G[q] = *reinterpret_cast<uint32_t*>(&h);
    }
}

// conv1 3x3 (1->16) SAME + relu + maxpool2
__global__ __launch_bounds__(256) void conv1_pool(const float* __restrict__ in,
                                                  const float* __restrict__ w,
                                                  const float* __restrict__ bias,
                                                  float* __restrict__ out) {
    int idx = blockIdx.x * 256 + threadIdx.x;
    if (idx >= 256 * 32 * 32 * 16) return;
    int c = idx & 15, x = (idx >> 4) & 31, y = (idx >> 9) & 31, b = idx >> 14;
    const float* inb = in + (size_t)b * 4096;
    float bv = bias[c];
    float mx = 0.0f;
    #pragma unroll
    for (int dy = 0; dy < 2; ++dy)
    #pragma unroll
    for (int dx = 0; dx < 2; ++dx) {
        int oy = 2 * y + dy, ox = 2 * x + dx;
        float s = bv;
        #pragma unroll
        for (int ky = 0; ky < 3; ++ky) {
            int iy = oy + ky - 1;
            if (iy < 0 || iy > 63) continue;
            #pragma unroll
            for (int kx = 0; kx < 3; ++kx) {
                int ix = ox + kx - 1;
                if (ix < 0 || ix > 63) continue;
                s = fmaf(inb[iy * 64 + ix], w[(ky * 3 + kx) * 16 + c], s);
            }
        }
        mx = fmaxf(mx, fmaxf(s, 0.0f));
    }
    out[idx] = mx;
}

// conv2 3x3 (16->32) SAME + relu + maxpool2
__global__ __launch_bounds__(256) void conv2_pool(const float* __restrict__ p1,
                                                  const float* __restrict__ w,
                                                  const float* __restrict__ bias,
                                                  float* __restrict__ seq) {
    int idx = blockIdx.x * 256 + threadIdx.x;
    if (idx >= 256 * 16 * 16 * 32) return;
    int c = idx & 31, x = (idx >> 5) & 15, y = (idx >> 9) & 15, b = idx >> 13;
    const float* pb = p1 + (size_t)b * (32 * 32 * 16);
    float bv = bias[c];
    float acc[4] = {bv, bv, bv, bv};
    #pragma unroll
    for (int ky = 0; ky < 3; ++ky)
    #pragma unroll
    for (int kx = 0; kx < 3; ++kx) {
        float w16[16];
        #pragma unroll
        for (int i = 0; i < 16; ++i) w16[i] = w[((ky * 3 + kx) * 16 + i) * 32 + c];
        #pragma unroll
        for (int dy = 0; dy < 2; ++dy)
        #pragma unroll
        for (int dx = 0; dx < 2; ++dx) {
            int iy = 2 * y + dy + ky - 1, ix = 2 * x + dx + kx - 1;
            if (iy < 0 || iy > 31 || ix < 0 || ix > 31) continue;
            const float4* pin4 = (const float4*)(pb + (iy * 32 + ix) * 16);
            float4 v0 = pin4[0], v1 = pin4[1], v2 = pin4[2], v3 = pin4[3];
            int a = dy * 2 + dx;
            acc[a] = fmaf(v0.x, w16[0], acc[a]);  acc[a] = fmaf(v0.y, w16[1], acc[a]);
            acc[a] = fmaf(v0.z, w16[2], acc[a]);  acc[a] = fmaf(v0.w, w16[3], acc[a]);
            acc[a] = fmaf(v1.x, w16[4], acc[a]);  acc[a] = fmaf(v1.y, w16[5], acc[a]);
            acc[a] = fmaf(v1.z, w16[6], acc[a]);  acc[a] = fmaf(v1.w, w16[7], acc[a]);
            acc[a] = fmaf(v2.x, w16[8], acc[a]);  acc[a] = fmaf(v2.y, w16[9], acc[a]);
            acc[a] = fmaf(v2.z, w16[10], acc[a]); acc[a] = fmaf(v2.w, w16[11], acc[a]);
            acc[a] = fmaf(v3.x, w16[12], acc[a]); acc[a] = fmaf(v3.y, w16[13], acc[a]);
            acc[a] = fmaf(v3.z, w16[14], acc[a]); acc[a] = fmaf(v3.w, w16[15], acc[a]);
        }
    }
    float mx = 0.0f;
    #pragma unroll
    for (int a = 0; a < 4; ++a) mx = fmaxf(mx, acc[a]);
    seq[idx] = mx;
}

// ---------------------------------------------------------------------------
// Grouped persistent NTM scan.
// ---------------------------------------------------------------------------
#define PSCLIP1(col_) fminf(fmaxf(pp[0][col_] + pp[1][col_] + pp[2][col_] + pp[3][col_] + hb[col_], -CLIPV), CLIPV)
#define D4(acc_, w_, v_) acc_ = dot2f((w_).w,(v_).w, dot2f((w_).z,(v_).z, dot2f((w_).y,(v_).y, dot2f((w_).x,(v_).x,(acc_)))));

__global__ __launch_bounds__(1024) void ntm_scan12(
    const float* __restrict__ seq,
    const uint32_t* __restrict__ WslG,
    const uint32_t* __restrict__ hw2G,
    const float* __restrict__ lb,
    const float* __restrict__ hb,
    const float* __restrict__ ow,
    const float* __restrict__ ob,
    const float* __restrict__ dw,
    const float* __restrict__ db,
    uint32_t* __restrict__ hEx,      // [256 gb][128] u32 (h pairs)
    uint32_t* __restrict__ rEx,      // [256 gb][16]  u32 (r pairs 0..9, pads 0)
    int* __restrict__ ctr,           // [32] group counters (memset 0 per launch)
    float* __restrict__ out)         // [256][2]
{
    __shared__ uint4 Wsl[40 * 128];                   // 81920 B
    __shared__ __align__(16) uint32_t aci[8][144];    // 4608 B  (x 0..15, h 16..143)
    __shared__ float zpartG[4][8][128];               // 16384 B
    __shared__ float Msh[MW][132];                    // 10560 B
    __shared__ float wprev[2][NLOC];                  // 1024 B
    __shared__ float pp[4][PC];                       // 1472 B
    __shared__ float evs[MW], avs[MW], rds[MW];       // 240 B
    __shared__ float o8[8];                           // 32 B
    // total ~116 KB -> 1 block/CU

    const int t = threadIdx.x;
    const int bb = blockIdx.x;
    const int g = bb & 31, m = bb >> 5;   // members of a group share bid%8 -> same XCD
    const int gb0 = g * 8;
    const int bHome = gb0 + m;
    int syncno = 0;

    auto gsync = [&](int n) {
        if (t == 0) {
            __hip_atomic_fetch_add(ctr + g, 1, __ATOMIC_RELEASE, __HIP_MEMORY_SCOPE_AGENT);
            while (__hip_atomic_load(ctr + g, __ATOMIC_RELAXED, __HIP_MEMORY_SCOPE_AGENT) < 8 * n)
                __builtin_amdgcn_s_sleep(2);
            (void)__hip_atomic_load(ctr + g, __ATOMIC_ACQUIRE, __HIP_MEMORY_SCOPE_AGENT);
        }
        __syncthreads();
    };

    // ---- load resident weight slice ----
    const uint4* WG4 = ((const uint4*)WslG) + (size_t)m * 5120;
    for (int i = t; i < 5120; i += 1024) Wsl[i] = WG4[i];

    // ---- init state ----
    for (int i = t; i < 8 * 144; i += 1024) {
        int b = i / 144, p = i - b * 144;
        uint32_t v = 0u;
        if (p < 16) {
            __half2 hh2 = __floats2half2_rn(seq[(size_t)(gb0 + b) * 8192 + 2 * p],
                                            seq[(size_t)(gb0 + b) * 8192 + 2 * p + 1]);
            v = *reinterpret_cast<uint32_t*>(&hh2);
        }
        aci[b][p] = v;
    }
    for (int i = t; i < MW * 132; i += 1024) Msh[i / 132][i - (i / 132) * 132] = 1e-6f;
    if (t < 256) wprev[t >> 7][t & 127] = 1.0f / 128.0f;
    if (t < 16) {
        __half2 hh2 = __floats2half2_rn(1e-6f, 1e-6f);
        rEx[bHome * 16 + t] = (t < 10) ? *reinterpret_cast<uint32_t*>(&hh2) : 0u;
    }
    float c_reg = 0.0f;   // LSTM cell: thread t<256 owns (b=t>>5, u=t&31)
    __syncthreads();
    gsync(++syncno);      // publish rEx init

    const int c = t & 127, b4 = (t >> 7) & 1, kq = t >> 8;

    for (int i = 0; i < 256; ++i) {
        // ---- A: P1 z-slice GEMM (8 batches, LDS weights, zero streaming) ----
        {
            float a0 = 0, a1 = 0, a2 = 0, a3 = 0;
            const uint4* ar0 = (const uint4*)&aci[b4 * 4 + 0][0];
            const uint4* ar1 = (const uint4*)&aci[b4 * 4 + 1][0];
            const uint4* ar2 = (const uint4*)&aci[b4 * 4 + 2][0];
            const uint4* ar3 = (const uint4*)&aci[b4 * 4 + 3][0];
            #pragma unroll
            for (int p2 = 0; p2 < 10; ++p2) {
                const int pb = kq * 10 + p2;
                uint4 w4 = Wsl[pb * 128 + c];
                uint4 v0, v1, v2, v3;
                if (kq == 3 && p2 >= 6) {       // pairs 144..159: reads from rEx
                    const uint4* rE4 = (const uint4*)rEx;
                    int o = p2 - 6;
                    v0 = rE4[(gb0 + b4 * 4 + 0) * 4 + o];
                    v1 = rE4[(gb0 + b4 * 4 + 1) * 4 + o];
                    v2 = rE4[(gb0 + b4 * 4 + 2) * 4 + o];
                    v3 = rE4[(gb0 + b4 * 4 + 3) * 4 + o];
                } else {
                    v0 = ar0[pb]; v1 = ar1[pb]; v2 = ar2[pb]; v3 = ar3[pb];
                }
                D4(a0, w4, v0) D4(a1, w4, v1) D4(a2, w4, v2) D4(a3, w4, v3)
            }
            zpartG[kq][b4 * 4 + 0][c] = a0;
            zpartG[kq][b4 * 4 + 1][c] = a1;
            zpartG[kq][b4 * 4 + 2][c] = a2;
            zpartG[kq][b4 * 4 + 3][c] = a3;
        }
        __syncthreads();   // B1

        // ---- B: LSTM (32 units x 8 batches) + hEx write + x prefetch ----
        if (t < 256) {
            const int b = t >> 5, u = t & 31;
            const int gu = m * 32 + u;
            float zi = lb[gu], zf = lb[256 + gu], zg = lb[512 + gu], zo = lb[768 + gu];
            #pragma unroll
            for (int q = 0; q < 4; ++q) {
                zi += zpartG[q][b][u];
                zf += zpartG[q][b][32 + u];
                zg += zpartG[q][b][64 + u];
                zo += zpartG[q][b][96 + u];
            }
            float cg = sigmoidf_(zf) * c_reg + sigmoidf_(zi) * tanhf(zg);
            c_reg = cg;
            float h = sigmoidf_(zo) * tanhf(cg);
            float hn = __shfl(h, ((t & 63) + 1) & 63, 64);
            if ((u & 1) == 0) {
                __half2 hh2 = __floats2half2_rn(h, hn);
                hEx[(gb0 + b) * 128 + m * 16 + (u >> 1)] = *reinterpret_cast<uint32_t*>(&hh2);
            }
        } else if (t >= 256 && t < 384 && i < 255) {
            int q = t - 256, b = q >> 4, j = q & 15;
            const float* xp = seq + (size_t)(gb0 + b) * 8192 + (size_t)(i + 1) * 32 + 2 * j;
            __half2 hh2 = __floats2half2_rn(xp[0], xp[1]);
            aci[b][j] = *reinterpret_cast<uint32_t*>(&hh2);
        }
        __syncthreads();   // B2
        gsync(++syncno);   // S1: h published

        // ---- C: P3 (home batch, from hEx) || hEx -> aci copy ----
        if (t < 368) {
            int kq2 = t / 92, col = t - kq2 * 92;
            const uint32_t* hwp = hw2G + kq2 * 32 * 92 + col;
            const uint32_t* hbp = hEx + bHome * 128 + kq2 * 32;
            float s = 0.0f;
            #pragma unroll 8
            for (int uu = 0; uu < 32; ++uu)
                s = dot2f(hwp[uu * 92], hbp[uu], s);
            pp[kq2][col] = s;
        } else if (t >= 384 && t < 896) {
            int q = t - 384, b = q >> 6, p = q & 63;
            const uint32_t* hr = hEx + (gb0 + b) * 128;
            aci[b][16 + p] = hr[p];
            aci[b][80 + p] = hr[64 + p];
        }
        __syncthreads();   // B4

        // ---- D: P4 addressing (home batch; 2 waves) + evs/avs ----
        if (t < 128) {
            const int l = t & 63, hh = t >> 6;
            const int hc = hh * 26;
            float beta  = softplusf_(PSCLIP1(hc + 20));
            float gte   = sigmoidf_(PSCLIP1(hc + 21));
            float s0r = PSCLIP1(hc + 22), s1r = PSCLIP1(hc + 23), s2r = PSCLIP1(hc + 24);
            float mS = fmaxf(s0r, fmaxf(s1r, s2r));
            float q0 = expf(s0r - mS), q1 = expf(s1r - mS), q2 = expf(s2r - mS);
            float qin = 1.0f / (q0 + q1 + q2);
            float sh0 = q0 * qin, sh1 = q1 * qin, sh2 = q2 * qin;
            float gamma = softplusf_(PSCLIP1(hc + 25)) + 1.0f;

            float kvv = (l < 20) ? tanhf(PSCLIP1(hc + l)) : 0.0f;
            float kn2 = kvv * kvv;
            #pragma unroll
            for (int o = 1; o < 64; o <<= 1) kn2 += __shfl_xor(kn2, o, 64);
            float kden = sqrtf(kn2) + 1e-8f;

            float d0 = 0, d1 = 0, m20 = 0, m21 = 0;
            #pragma unroll
            for (int wi = 0; wi < 20; ++wi) {
                float kk = __shfl(kvv, wi, 64);
                float2 mv = *reinterpret_cast<const float2*>(&Msh[wi][2 * l]);
                d0  = fmaf(kk, mv.x, d0);      d1  = fmaf(kk, mv.y, d1);
                m20 = fmaf(mv.x, mv.x, m20);   m21 = fmaf(mv.y, mv.y, m21);
            }
            float x0 = beta * (d0 / ((sqrtf(m20) + 1e-8f) * kden));
            float x1 = beta * (d1 / ((sqrtf(m21) + 1e-8f) * kden));
            float mx = fmaxf(x0, x1);
            #pragma unroll
            for (int o = 1; o < 64; o <<= 1) mx = fmaxf(mx, __shfl_xor(mx, o, 64));
            float e0 = expf(x0 - mx), e1 = expf(x1 - mx);
            float se = e0 + e1;
            #pragma unroll
            for (int o = 1; o < 64; o <<= 1) se += __shfl_xor(se, o, 64);
            float inv = 1.0f / se;
            float2 wpv = *reinterpret_cast<const float2*>(&wprev[hh][2 * l]);
            float wg0 = gte * (e0 * inv) + (1.0f - gte) * wpv.x;
            float wg1 = gte * (e1 * inv) + (1.0f - gte) * wpv.y;
            float wgm = __shfl(wg1, (l + 63) & 63, 64);
            float wgp = __shfl(wg0, (l + 1) & 63, 64);
            float wt0 = sh0 * wg1 + sh1 * wg0 + sh2 * wgm;
            float wt1 = sh0 * wgp + sh1 * wg1 + sh2 * wg0;
            float wpw0 = expf(gamma * logf(wt0 + 1e-8f));
            float wpw1 = expf(gamma * logf(wt1 + 1e-8f));
            float ssum = wpw0 + wpw1;
            #pragma unroll
            for (int o = 1; o < 64; o <<= 1) ssum += __shfl_xor(ssum, o, 64);
            float rin = 1.0f / ssum;
            *reinterpret_cast<float2*>(&wprev[hh][2 * l]) = make_float2(wpw0 * rin, wpw1 * rin);
        } else if (t < 168) {
            int r2 = t - 128;
            if (r2 < 20) evs[r2]      = sigmoidf_(PSCLIP1(52 + r2));
            else         avs[r2 - 20] = tanhf(PSCLIP1(72 + (r2 - 20)));
        }
        __syncthreads();   // B5

        // ---- E: P5 fused read + erase/add + rEx publish ----
        if (t < 320) {
            int wi = t >> 4, l16 = t & 15;
            int n0 = l16 * 8;
            float ev = evs[wi], av = avs[wi];
            float s = 0.0f;
            #pragma unroll
            for (int n = n0; n < n0 + 8; ++n) {
                float mv = Msh[wi][n];
                s = fmaf(wprev[0][n], mv, s);
                float wwn = wprev[1][n];
                Msh[wi][n] = mv * (1.0f - wwn * ev) + wwn * av;
            }
            s += __shfl_xor(s, 1, 64); s += __shfl_xor(s, 2, 64);
            s += __shfl_xor(s, 4, 64); s += __shfl_xor(s, 8, 64);
            float rodd = __shfl(s, (t & 63) ^ 16, 64);
            if ((t & 31) == 0) {
                __half2 hp = __floats2half2_rn(s, rodd);
                rEx[bHome * 16 + (wi >> 1)] = *reinterpret_cast<uint32_t*>(&hp);
            }
            if (l16 == 0) rds[wi] = s;
        }
        __syncthreads();   // B6
        gsync(++syncno);   // S2: r published
    }

    // ---- final NTM output head + dense + softmax (home batch) ----
    if (t < 8) {
        float s = ob[t];
        const _Float16* hrow = reinterpret_cast<const _Float16*>(&aci[m][0]);
        for (int u = 0; u < 256; ++u) s = fmaf((float)hrow[32 + u], ow[u * 8 + t], s);
        #pragma unroll
        for (int wi = 0; wi < 20; ++wi) s = fmaf(rds[wi], ow[(256 + wi) * 8 + t], s);
        o8[t] = fminf(fmaxf(s, -CLIPV), CLIPV);
    }
    __syncthreads();
    if (t == 0) {
        float l0 = db[0], l1 = db[1];
        #pragma unroll
        for (int k = 0; k < 8; ++k) {
            float v = o8[k];
            l0 = fmaf(v, dw[k * 2 + 0], l0);
            l1 = fmaf(v, dw[k * 2 + 1], l1);
        }
        float mm2 = fmaxf(l0, l1);
        float q0 = expf(l0 - mm2), q1 = expf(l1 - mm2);
        float inv = 1.0f / (q0 + q1);
        out[bHome * 2 + 0] = q0 * inv;
        out[bHome * 2 + 1] = q1 * inv;
    }
}

extern "C" void kernel_launch(void* const* d_in, const int* in_sizes, int n_in,
                              void* d_out, int out_size, void* d_ws, size_t ws_size,
                              hipStream_t stream) {
    const float* inputs = (const float*)d_in[0];
    const float* c1w = (const float*)d_in[1];
    const float* c1b = (const float*)d_in[2];
    const float* c2w = (const float*)d_in[3];
    const float* c2b = (const float*)d_in[4];
    const float* lwx = (const float*)d_in[5];
    const float* lwh = (const float*)d_in[6];
    const float* lb  = (const float*)d_in[7];
    const float* hw  = (const float*)d_in[8];
    const float* hb  = (const float*)d_in[9];
    const float* ow  = (const float*)d_in[10];
    const float* ob  = (const float*)d_in[11];
    const float* dw  = (const float*)d_in[12];
    const float* db  = (const float*)d_in[13];
    float* out = (float*)d_out;

    float* ws  = (float*)d_ws;
    float* p1  = ws;                               // 4,194,304 f
    float* seq = ws + 4194304;                     // 2,097,152 f
    uint32_t* WslG = (uint32_t*)(ws + 6291456);    // 163,840 u32
    uint32_t* hw2G = WslG + 163840;                //  11,776 u32
    uint32_t* hEx  = hw2G + 11776;                 //  32,768 u32
    uint32_t* rEx  = hEx + 32768;                  //   4,096 u32
    int*      ctr  = (int*)(rEx + 4096);           //      32 i32

    hipMemsetAsync(ctr, 0, 32 * sizeof(int), stream);
    hipLaunchKernelGGL(prep_pack,   dim3(686),   dim3(256),  0, stream, lwx, lwh, hw, WslG, hw2G);
    hipLaunchKernelGGL(conv1_pool,  dim3(16384), dim3(256),  0, stream, inputs, c1w, c1b, p1);
    hipLaunchKernelGGL(conv2_pool,  dim3(8192),  dim3(256),  0, stream, p1, c2w, c2b, seq);
    hipLaunchKernelGGL(ntm_scan12,  dim3(256),   dim3(1024), 0, stream,
                       seq, WslG, hw2G, lb, hb, ow, ob, dw, db, hEx, rEx, ctr, out);
}

// Round 13
// 1931.766 us; speedup vs baseline: 4.3916x; 4.3916x over previous
//
#include <hip/hip_runtime.h>
#include <hip/hip_fp16.h>
#include <cstdint>
#include <cstddef>

// ---------------------------------------------------------------------------
// CNN (conv1+pool, conv2+pool) -> seq [256][256][32]
// NTM scan: 256 blocks x 1024 threads, 1 batch/block, 1 block/CU.
// TWO __syncthreads per step + 2 LDS sub-barriers (6 chain waves only):
//  REGION i:
//    waves 0..7  : full z-GEMM step i (144 pairs: 32 LDS-resident 128KB,
//                  112 streamed 448KB as ONE uninterrupted burst)
//    waves 8..13 : NTM chain step i-1 at full density:
//                  P3(368t) -[subsync]- P4(128t)+ea(40t) -[subsync]- P5(320t)
//    wave 14     : prefetch x_{i+1} -> xbuf
//  LSTM i: z = sum(zpart) + WrT*rp + bias -> h_i; copy xbuf -> aci.
// Reads enter z ONLY via rp (10 fp16 pairs) x WrT (R8-R10 trick).
// ci slots (u32 pairs): x 0..15, h 16..143. Chain state (M, wprev, rp) in LDS.
// ---------------------------------------------------------------------------

#define MW    20
#define NLOC  128
#define ZC    1024
#define PC    92
#define CLIPV 20.0f

__device__ __forceinline__ float sigmoidf_(float x) { return 1.0f / (1.0f + expf(-x)); }
__device__ __forceinline__ float softplusf_(float x) { return log1pf(expf(x)); }

__device__ __forceinline__ float dot2f(uint32_t w, uint32_t a, float c) {
    asm("v_dot2_f32_f16 %0, %1, %2, %0" : "+v"(c) : "v"(w), "v"(a));
    return c;
}

// pair row map (144 pairs): k<32 -> wx row k (x); k in [32,288) -> wh row k-32
__device__ __forceinline__ float wvalA(const float* wx, const float* wh, int k, int col) {
    return (k < 32) ? wx[k * ZC + col] : wh[(k - 32) * ZC + col];
}
__device__ __forceinline__ uint32_t packA(const float* wx, const float* wh, int pr, int col) {
    __half2 h = __floats2half2_rn(wvalA(wx, wh, 2 * pr, col), wvalA(wx, wh, 2 * pr + 1, col));
    return *reinterpret_cast<uint32_t*>(&h);
}

// WG8: u32 idx = ((pr*2 + j)*128 + c)*4 + m -> col = 8c + 4j + m, pr 0..143.
// WrT: [1024 cols][12] u32 (reads pairs q<10: wx rows 32..51), else 0.
// hw2: [128 up][92 col] u32.
__global__ __launch_bounds__(256) void prep_pack(const float* __restrict__ wx,
                                                 const float* __restrict__ wh,
                                                 const float* __restrict__ hw,
                                                 uint32_t* __restrict__ WG8,
                                                 uint32_t* __restrict__ WrT,
                                                 uint32_t* __restrict__ hw2) {
    int idx = blockIdx.x * 256 + threadIdx.x;
    if (idx < 147456) {
        int m = idx & 3, c = (idx >> 2) & 127, j = (idx >> 9) & 1, pr = idx >> 10;
        WG8[idx] = packA(wx, wh, pr, 8 * c + 4 * j + m);
    } else if (idx < 159744) {
        int q2 = idx - 147456;
        int col = q2 / 12, q = q2 - col * 12;
        if (q < 10) {
            __half2 h = __floats2half2_rn(wx[(32 + 2 * q) * ZC + col], wx[(33 + 2 * q) * ZC + col]);
            WrT[q2] = *reinterpret_cast<uint32_t*>(&h);
        } else WrT[q2] = 0u;
    } else if (idx < 171520) {
        int q3 = idx - 159744;
        int up = q3 / 92, col = q3 - up * 92;
        __half2 h = __floats2half2_rn(hw[(2 * up) * PC + col], hw[(2 * up + 1) * PC + col]);
        hw2[q3] = *reinterpret_cast<uint32_t*>(&h);
    }
}

// conv1 3x3 (1->16) SAME + relu + maxpool2
__global__ __launch_bounds__(256) void conv1_pool(const float* __restrict__ in,
                                                  const float* __restrict__ w,
                                                  const float* __restrict__ bias,
                                                  float* __restrict__ out) {
    int idx = blockIdx.x * 256 + threadIdx.x;
    if (idx >= 256 * 32 * 32 * 16) return;
    int c = idx & 15, x = (idx >> 4) & 31, y = (idx >> 9) & 31, b = idx >> 14;
    const float* inb = in + (size_t)b * 4096;
    float bv = bias[c];
    float mx = 0.0f;
    #pragma unroll
    for (int dy = 0; dy < 2; ++dy)
    #pragma unroll
    for (int dx = 0; dx < 2; ++dx) {
        int oy = 2 * y + dy, ox = 2 * x + dx;
        float s = bv;
        #pragma unroll
        for (int ky = 0; ky < 3; ++ky) {
            int iy = oy + ky - 1;
            if (iy < 0 || iy > 63) continue;
            #pragma unroll
            for (int kx = 0; kx < 3; ++kx) {
                int ix = ox + kx - 1;
                if (ix < 0 || ix > 63) continue;
                s = fmaf(inb[iy * 64 + ix], w[(ky * 3 + kx) * 16 + c], s);
            }
        }
        mx = fmaxf(mx, fmaxf(s, 0.0f));
    }
    out[idx] = mx;
}

// conv2 3x3 (16->32) SAME + relu + maxpool2
__global__ __launch_bounds__(256) void conv2_pool(const float* __restrict__ p1,
                                                  const float* __restrict__ w,
                                                  const float* __restrict__ bias,
                                                  float* __restrict__ seq) {
    int idx = blockIdx.x * 256 + threadIdx.x;
    if (idx >= 256 * 16 * 16 * 32) return;
    int c = idx & 31, x = (idx >> 5) & 15, y = (idx >> 9) & 15, b = idx >> 13;
    const float* pb = p1 + (size_t)b * (32 * 32 * 16);
    float bv = bias[c];
    float acc[4] = {bv, bv, bv, bv};
    #pragma unroll
    for (int ky = 0; ky < 3; ++ky)
    #pragma unroll
    for (int kx = 0; kx < 3; ++kx) {
        float w16[16];
        #pragma unroll
        for (int i = 0; i < 16; ++i) w16[i] = w[((ky * 3 + kx) * 16 + i) * 32 + c];
        #pragma unroll
        for (int dy = 0; dy < 2; ++dy)
        #pragma unroll
        for (int dx = 0; dx < 2; ++dx) {
            int iy = 2 * y + dy + ky - 1, ix = 2 * x + dx + kx - 1;
            if (iy < 0 || iy > 31 || ix < 0 || ix > 31) continue;
            const float4* pin4 = (const float4*)(pb + (iy * 32 + ix) * 16);
            float4 v0 = pin4[0], v1 = pin4[1], v2 = pin4[2], v3 = pin4[3];
            int a = dy * 2 + dx;
            acc[a] = fmaf(v0.x, w16[0], acc[a]);  acc[a] = fmaf(v0.y, w16[1], acc[a]);
            acc[a] = fmaf(v0.z, w16[2], acc[a]);  acc[a] = fmaf(v0.w, w16[3], acc[a]);
            acc[a] = fmaf(v1.x, w16[4], acc[a]);  acc[a] = fmaf(v1.y, w16[5], acc[a]);
            acc[a] = fmaf(v1.z, w16[6], acc[a]);  acc[a] = fmaf(v1.w, w16[7], acc[a]);
            acc[a] = fmaf(v2.x, w16[8], acc[a]);  acc[a] = fmaf(v2.y, w16[9], acc[a]);
            acc[a] = fmaf(v2.z, w16[10], acc[a]); acc[a] = fmaf(v2.w, w16[11], acc[a]);
            acc[a] = fmaf(v3.x, w16[12], acc[a]); acc[a] = fmaf(v3.y, w16[13], acc[a]);
            acc[a] = fmaf(v3.z, w16[14], acc[a]); acc[a] = fmaf(v3.w, w16[15], acc[a]);
        }
    }
    float mx = 0.0f;
    #pragma unroll
    for (int a = 0; a < 4; ++a) mx = fmaxf(mx, acc[a]);
    seq[idx] = mx;
}

// ---------------------------------------------------------------------------
// Persistent NTM scan, wave-specialized with LDS sub-barriers.
// ---------------------------------------------------------------------------
#define PSCLIP1(col_) fminf(fmaxf(pp[0][col_] + pp[1][col_] + pp[2][col_] + pp[3][col_] + hb[col_], -CLIPV), CLIPV)

__global__ __launch_bounds__(1024, 4) void ntm_scan13(
    const float* __restrict__ seq,
    const uint32_t* __restrict__ WG8,
    const uint32_t* __restrict__ WrT,
    const uint32_t* __restrict__ hw2G,
    const float* __restrict__ lb,
    const float* __restrict__ hb,
    const float* __restrict__ ow,
    const float* __restrict__ ob,
    const float* __restrict__ dw,
    const float* __restrict__ db,
    float* __restrict__ out)          // [256][2]
{
    __shared__ uint4 Wl4[32 * 2 * 128];               // 131072 B (8 pairs per K-quarter)
    __shared__ float zpart[4][ZC];                    // 16384 B
    __shared__ __align__(16) uint32_t aci[160];       // 640 B (x 0..15, h 16..143)
    __shared__ uint32_t xbuf[16];                     // 64 B
    __shared__ float Msh[MW][132];                    // 10560 B
    __shared__ float wprev[2][NLOC];                  // 1024 B
    __shared__ float pp[4][PC];                       // 1472 B
    __shared__ float evs[MW], avs[MW], rds[MW];       // 240 B
    __shared__ uint32_t rp[10];                       // 40 B
    __shared__ float o8[8];                           // 32 B
    __shared__ int sflag;                             // 4 B
    // total ~161.5 KB -> 1 block/CU

    const int t = threadIdx.x;
    const int bb = blockIdx.x;
    const uint4* WGV = (const uint4*)WG8;

    // ---- stage resident pairs: per K-quarter kq (36 pairs), pairs 0..7 ----
    for (int i = t; i < 8192; i += 1024) {
        int lp = i >> 8, j = (i >> 7) & 1, c = i & 127;
        int gp = (lp >> 3) * 36 + (lp & 7);
        Wl4[i] = WGV[(gp * 2 + j) * 128 + c];
    }

    // ---- init state ----
    if (t < 160) {
        uint32_t v = 0u;
        if (t < 16) {
            __half2 hh2 = __floats2half2_rn(seq[(size_t)bb * 8192 + 2 * t],
                                            seq[(size_t)bb * 8192 + 2 * t + 1]);
            v = *reinterpret_cast<uint32_t*>(&hh2);
        }
        aci[t] = v;
    }
    for (int i = t; i < MW * 132; i += 1024)
        Msh[i / 132][i - (i / 132) * 132] = 1e-6f;
    if (t < 256) wprev[t >> 7][t & 127] = 1.0f / 128.0f;
    if (t < 10) {
        __half2 hh2 = __floats2half2_rn(1e-6f, 1e-6f);
        rp[t] = *reinterpret_cast<uint32_t*>(&hh2);
    }
    if (t == 0) sflag = 0;
    float c_reg = 0.0f;   // LSTM cell: thread t<256 owns u=t
    __syncthreads();

    int svc = 0;
    auto subsync = [&]() {
        svc += 6;
        __threadfence_block();
        if ((t & 63) == 0)
            __hip_atomic_fetch_add(&sflag, 1, __ATOMIC_RELAXED, __HIP_MEMORY_SCOPE_WORKGROUP);
        while (__hip_atomic_load(&sflag, __ATOMIC_RELAXED, __HIP_MEMORY_SCOPE_WORKGROUP) < svc)
            __builtin_amdgcn_s_sleep(1);
        __threadfence_block();
    };

    // ---- chain phase bodies (waves 8..13, pt = t-512) ----
    auto doP3 = [&](int pt) {
        if (pt < 368) {
            int kq2 = pt / 92, col = pt - kq2 * 92;
            const uint32_t* hwp = hw2G + kq2 * 32 * 92 + col;
            const uint32_t* hbp = aci + 16 + kq2 * 32;
            float s = 0.0f;
            #pragma unroll 8
            for (int uu = 0; uu < 32; ++uu)
                s = dot2f(hwp[uu * 92], hbp[uu], s);
            pp[kq2][col] = s;
        }
    };
    auto doP4 = [&](int pt) {
        if (pt < 128) {
            const int l = pt & 63, hh = pt >> 6;
            const int hc = hh * 26;
            float beta  = softplusf_(PSCLIP1(hc + 20));
            float gte   = sigmoidf_(PSCLIP1(hc + 21));
            float s0r = PSCLIP1(hc + 22), s1r = PSCLIP1(hc + 23), s2r = PSCLIP1(hc + 24);
            float mS = fmaxf(s0r, fmaxf(s1r, s2r));
            float q0 = expf(s0r - mS), q1 = expf(s1r - mS), q2 = expf(s2r - mS);
            float qin = 1.0f / (q0 + q1 + q2);
            float sh0 = q0 * qin, sh1 = q1 * qin, sh2 = q2 * qin;
            float gamma = softplusf_(PSCLIP1(hc + 25)) + 1.0f;

            float kvv = (l < 20) ? tanhf(PSCLIP1(hc + l)) : 0.0f;
            float kn2 = kvv * kvv;
            #pragma unroll
            for (int o = 1; o < 64; o <<= 1) kn2 += __shfl_xor(kn2, o, 64);
            float kden = sqrtf(kn2) + 1e-8f;

            float d0 = 0, d1 = 0, m20 = 0, m21 = 0;
            #pragma unroll
            for (int wi = 0; wi < 20; ++wi) {
                float kk = __shfl(kvv, wi, 64);
                float2 mv = *reinterpret_cast<const float2*>(&Msh[wi][2 * l]);
                d0  = fmaf(kk, mv.x, d0);      d1  = fmaf(kk, mv.y, d1);
                m20 = fmaf(mv.x, mv.x, m20);   m21 = fmaf(mv.y, mv.y, m21);
            }
            float x0 = beta * (d0 / ((sqrtf(m20) + 1e-8f) * kden));
            float x1 = beta * (d1 / ((sqrtf(m21) + 1e-8f) * kden));
            float mx = fmaxf(x0, x1);
            #pragma unroll
            for (int o = 1; o < 64; o <<= 1) mx = fmaxf(mx, __shfl_xor(mx, o, 64));
            float e0 = expf(x0 - mx), e1 = expf(x1 - mx);
            float se = e0 + e1;
            #pragma unroll
            for (int o = 1; o < 64; o <<= 1) se += __shfl_xor(se, o, 64);
            float inv = 1.0f / se;
            float2 wpv = *reinterpret_cast<const float2*>(&wprev[hh][2 * l]);
            float wg0 = gte * (e0 * inv) + (1.0f - gte) * wpv.x;
            float wg1 = gte * (e1 * inv) + (1.0f - gte) * wpv.y;
            float wgm = __shfl(wg1, (l + 63) & 63, 64);
            float wgp = __shfl(wg0, (l + 1) & 63, 64);
            float wt0 = sh0 * wg1 + sh1 * wg0 + sh2 * wgm;
            float wt1 = sh0 * wgp + sh1 * wg1 + sh2 * wg0;
            float wpw0 = expf(gamma * logf(wt0 + 1e-8f));
            float wpw1 = expf(gamma * logf(wt1 + 1e-8f));
            float ssum = wpw0 + wpw1;
            #pragma unroll
            for (int o = 1; o < 64; o <<= 1) ssum += __shfl_xor(ssum, o, 64);
            float rin = 1.0f / ssum;
            *reinterpret_cast<float2*>(&wprev[hh][2 * l]) = make_float2(wpw0 * rin, wpw1 * rin);
        } else if (pt < 168) {
            int r2 = pt - 128;
            if (r2 < 20) evs[r2]      = sigmoidf_(PSCLIP1(52 + r2));
            else         avs[r2 - 20] = tanhf(PSCLIP1(72 + (r2 - 20)));
        }
    };
    auto doP5 = [&](int pt) {
        if (pt < 320) {
            int wi = pt >> 4, l16 = pt & 15;
            int n0 = l16 * 8;
            float ev = evs[wi], av = avs[wi];
            float s = 0.0f;
            #pragma unroll
            for (int n = n0; n < n0 + 8; ++n) {
                float mv = Msh[wi][n];
                s = fmaf(wprev[0][n], mv, s);
                float wwn = wprev[1][n];
                Msh[wi][n] = mv * (1.0f - wwn * ev) + wwn * av;
            }
            s += __shfl_xor(s, 1, 64); s += __shfl_xor(s, 2, 64);
            s += __shfl_xor(s, 4, 64); s += __shfl_xor(s, 8, 64);
            float sodd = __shfl_xor(s, 16, 64);
            if (l16 == 0) {
                rds[wi] = s;
                if ((wi & 1) == 0) {
                    __half2 hp = __floats2half2_rn(s, sodd);
                    rp[wi >> 1] = *reinterpret_cast<uint32_t*>(&hp);
                }
            }
        }
    };

    for (int i = 0; i < 256; ++i) {
        // ========= REGION: z-GEMM(i) || chain(i-1) || x-prefetch =========
        if (t < 512) {
            const int kq = t >> 7, c = t & 127;
            const int prb = kq * 36;
            float a0 = 0, a1 = 0, a2 = 0, a3 = 0, a4 = 0, a5 = 0, a6 = 0, a7 = 0;
            const uint4* cap = (const uint4*)(aci + prb);
            #pragma unroll
            for (int g = 0; g < 9; ++g) {
                uint4 A = cap[g];
                uint32_t aa[4] = {A.x, A.y, A.z, A.w};
                #pragma unroll
                for (int q = 0; q < 4; ++q) {
                    const int p = g * 4 + q;
                    uint4 w0, w1;
                    if (p < 8) {
                        w0 = Wl4[((kq * 8 + p) * 2 + 0) * 128 + c];
                        w1 = Wl4[((kq * 8 + p) * 2 + 1) * 128 + c];
                    } else {
                        w0 = WGV[((prb + p) * 2 + 0) * 128 + c];
                        w1 = WGV[((prb + p) * 2 + 1) * 128 + c];
                    }
                    a0 = dot2f(w0.x, aa[q], a0); a1 = dot2f(w0.y, aa[q], a1);
                    a2 = dot2f(w0.z, aa[q], a2); a3 = dot2f(w0.w, aa[q], a3);
                    a4 = dot2f(w1.x, aa[q], a4); a5 = dot2f(w1.y, aa[q], a5);
                    a6 = dot2f(w1.z, aa[q], a6); a7 = dot2f(w1.w, aa[q], a7);
                }
            }
            *reinterpret_cast<float4*>(&zpart[kq][8 * c])     = make_float4(a0, a1, a2, a3);
            *reinterpret_cast<float4*>(&zpart[kq][8 * c + 4]) = make_float4(a4, a5, a6, a7);
        } else if (t < 896) {
            if (i > 0) {
                const int pt = t - 512;
                doP3(pt);
                subsync();
                doP4(pt);
                subsync();
                doP5(pt);
            }
        } else if (t < 912 && i < 255) {
            int j = t - 896;
            const float* xp = seq + (size_t)bb * 8192 + (size_t)(i + 1) * 32 + 2 * j;
            __half2 hh2 = __floats2half2_rn(xp[0], xp[1]);
            xbuf[j] = *reinterpret_cast<uint32_t*>(&hh2);
        }
        __syncthreads();   // B1

        // ========= LSTM i (+ xbuf -> aci copy) =========
        if (t < 256) {
            uint32_t rp0 = rp[0], rp1 = rp[1], rp2 = rp[2], rp3 = rp[3];
            uint32_t rp4 = rp[4], rp5 = rp[5], rp6 = rp[6], rp7 = rp[7];
            uint32_t rp8 = rp[8], rp9 = rp[9];
            float zg4[4];
            #pragma unroll
            for (int g4 = 0; g4 < 4; ++g4) {
                const uint4* wp = (const uint4*)(WrT + ((g4 << 8) + t) * 12);
                uint4 A = wp[0], B = wp[1], C = wp[2];
                float s = 0.0f;
                s = dot2f(A.x, rp0, s); s = dot2f(A.y, rp1, s);
                s = dot2f(A.z, rp2, s); s = dot2f(A.w, rp3, s);
                s = dot2f(B.x, rp4, s); s = dot2f(B.y, rp5, s);
                s = dot2f(B.z, rp6, s); s = dot2f(B.w, rp7, s);
                s = dot2f(C.x, rp8, s); s = dot2f(C.y, rp9, s);
                zg4[g4] = s;
            }
            float zi = lb[t]       + zg4[0] + zpart[0][t]       + zpart[1][t]       + zpart[2][t]       + zpart[3][t];
            float zf = lb[256 + t] + zg4[1] + zpart[0][256 + t] + zpart[1][256 + t] + zpart[2][256 + t] + zpart[3][256 + t];
            float zg = lb[512 + t] + zg4[2] + zpart[0][512 + t] + zpart[1][512 + t] + zpart[2][512 + t] + zpart[3][512 + t];
            float zo = lb[768 + t] + zg4[3] + zpart[0][768 + t] + zpart[1][768 + t] + zpart[2][768 + t] + zpart[3][768 + t];
            float cg = sigmoidf_(zf) * c_reg + sigmoidf_(zi) * tanhf(zg);
            c_reg = cg;
            reinterpret_cast<_Float16*>(aci)[32 + t] = (_Float16)(sigmoidf_(zo) * tanhf(cg));
        } else if (t >= 256 && t < 272 && i < 255) {
            aci[t - 256] = xbuf[t - 256];
        }
        __syncthreads();   // B2
    }

    // ---- epilogue: chain for step 255 ----
    if (t >= 512 && t < 896) {
        const int pt = t - 512;
        doP3(pt);
        subsync();
        doP4(pt);
        subsync();
        doP5(pt);
    }
    __syncthreads();

    // ---- final NTM output head + dense + softmax ----
    if (t < 8) {
        float s = ob[t];
        const _Float16* hrow = reinterpret_cast<const _Float16*>(aci);
        for (int u = 0; u < 256; ++u) s = fmaf((float)hrow[32 + u], ow[u * 8 + t], s);
        #pragma unroll
        for (int wi = 0; wi < 20; ++wi) s = fmaf(rds[wi], ow[(256 + wi) * 8 + t], s);
        o8[t] = fminf(fmaxf(s, -CLIPV), CLIPV);
    }
    __syncthreads();
    if (t == 0) {
        float l0 = db[0], l1 = db[1];
        #pragma unroll
        for (int k = 0; k < 8; ++k) {
            float v = o8[k];
            l0 = fmaf(v, dw[k * 2 + 0], l0);
            l1 = fmaf(v, dw[k * 2 + 1], l1);
        }
        float m = fmaxf(l0, l1);
        float q0 = expf(l0 - m), q1 = expf(l1 - m);
        float inv = 1.0f / (q0 + q1);
        out[bb * 2 + 0] = q0 * inv;
        out[bb * 2 + 1] = q1 * inv;
    }
}

extern "C" void kernel_launch(void* const* d_in, const int* in_sizes, int n_in,
                              void* d_out, int out_size, void* d_ws, size_t ws_size,
                              hipStream_t stream) {
    const float* inputs = (const float*)d_in[0];
    const float* c1w = (const float*)d_in[1];
    const float* c1b = (const float*)d_in[2];
    const float* c2w = (const float*)d_in[3];
    const float* c2b = (const float*)d_in[4];
    const float* lwx = (const float*)d_in[5];
    const float* lwh = (const float*)d_in[6];
    const float* lb  = (const float*)d_in[7];
    const float* hw  = (const float*)d_in[8];
    const float* hb  = (const float*)d_in[9];
    const float* ow  = (const float*)d_in[10];
    const float* ob  = (const float*)d_in[11];
    const float* dw  = (const float*)d_in[12];
    const float* db  = (const float*)d_in[13];
    float* out = (float*)d_out;

    float* ws  = (float*)d_ws;
    float* p1  = ws;                             // 4,194,304 f
    float* seq = ws + 4194304;                   // 2,097,152 f
    uint32_t* WG8  = (uint32_t*)(ws + 6291456);  // 147,456 u32
    uint32_t* WrT  = WG8 + 147456;               //  12,288 u32
    uint32_t* hw2G = WrT + 12288;                //  11,776 u32

    hipLaunchKernelGGL(prep_pack,   dim3(670),   dim3(256),  0, stream, lwx, lwh, hw, WG8, WrT, hw2G);
    hipLaunchKernelGGL(conv1_pool,  dim3(16384), dim3(256),  0, stream, inputs, c1w, c1b, p1);
    hipLaunchKernelGGL(conv2_pool,  dim3(8192),  dim3(256),  0, stream, p1, c2w, c2b, seq);
    hipLaunchKernelGGL(ntm_scan13,  dim3(256),   dim3(1024), 0, stream,
                       seq, WG8, WrT, hw2G, lb, hb, ow, ob, dw, db, out);
}